// Round 1
// baseline (1413.819 us; speedup 1.0000x reference)
//
#include <hip/hip_runtime.h>
#include <math.h>

#define EPS_C 0.001f
#define BATCH 16384

__device__ __forceinline__ float wave_sum(float s) {
  #pragma unroll
  for (int off = 32; off > 0; off >>= 1) s += __shfl_xor(s, off);
  return s;
}

// ---------------- H = X^T X + eps*I  (1152x1152) ----------------
__global__ __launch_bounds__(256) void k_xtx(const float* __restrict__ X, float* __restrict__ H) {
  __shared__ float sA[32][65];
  __shared__ float sB[32][65];
  const int t = threadIdx.x;
  const int bi = blockIdx.x * 64, bj = blockIdx.y * 64;
  const int tj = t & 15, ti = t >> 4;
  float acc[4][4] = {};
  for (int k0 = 0; k0 < 1152; k0 += 32) {
    #pragma unroll
    for (int l = 0; l < 2; ++l) {
      int idx = t + l * 256;
      int kk = idx >> 4, c4 = (idx & 15) << 2;
      float4 va = *(const float4*)&X[(k0 + kk) * 1152 + bi + c4];
      sA[kk][c4 + 0] = va.x; sA[kk][c4 + 1] = va.y; sA[kk][c4 + 2] = va.z; sA[kk][c4 + 3] = va.w;
      float4 vb = *(const float4*)&X[(k0 + kk) * 1152 + bj + c4];
      sB[kk][c4 + 0] = vb.x; sB[kk][c4 + 1] = vb.y; sB[kk][c4 + 2] = vb.z; sB[kk][c4 + 3] = vb.w;
    }
    __syncthreads();
    #pragma unroll
    for (int kk = 0; kk < 32; ++kk) {
      float am[4], bn[4];
      #pragma unroll
      for (int q = 0; q < 4; ++q) am[q] = sA[kk][ti * 4 + q];
      #pragma unroll
      for (int q = 0; q < 4; ++q) bn[q] = sB[kk][tj * 4 + q];
      #pragma unroll
      for (int r = 0; r < 4; ++r)
        #pragma unroll
        for (int c = 0; c < 4; ++c)
          acc[r][c] = fmaf(am[r], bn[c], acc[r][c]);
    }
    __syncthreads();
  }
  #pragma unroll
  for (int r = 0; r < 4; ++r) {
    int gi = bi + ti * 4 + r;
    float vv[4];
    #pragma unroll
    for (int c = 0; c < 4; ++c) {
      vv[c] = acc[r][c];
      if (gi == bj + tj * 4 + c) vv[c] += EPS_C;
    }
    float4 o = make_float4(vv[0], vv[1], vv[2], vv[3]);
    *(float4*)&H[gi * 1152 + bj + tj * 4] = o;
  }
}

// ---------------- assemble A=E^T, D11, Lam ----------------
// E[a][b] = 0.5*(H[a][b] + H[640+a][640+b] + Y[a][b] - Y[b][a]);  A[r][c] = E[c][r]
__global__ void k_assemble(const float* __restrict__ H, const float* __restrict__ Y,
                           float* __restrict__ A, float* __restrict__ D11, float* __restrict__ Lam) {
  int idx = blockIdx.x * 256 + threadIdx.x;
  if (idx < 512 * 512) {
    int r = idx >> 9, c = idx & 511;
    A[idx] = 0.5f * (H[c * 1152 + r] + H[(640 + c) * 1152 + 640 + r] + Y[c * 512 + r] - Y[r * 512 + c]);
  } else if (idx < 512 * 512 + 128 * 128) {
    int q = idx - 512 * 512;
    int i = q >> 7, j = q & 127;
    D11[q] = (j < i) ? -H[(512 + i) * 1152 + 512 + j] : 0.0f;
  } else if (idx < 512 * 512 + 128 * 128 + 128) {
    int i = idx - 512 * 512 - 128 * 128;
    Lam[i] = 0.5f * H[(512 + i) * 1152 + 512 + i];
  }
}

// ---------------- xc = -H21 @ x0 (128), Fx = H31 @ x0 (512) ----------------
__global__ void k_xcfx(const float* __restrict__ H, const float* __restrict__ x0,
                       float* __restrict__ xc, float* __restrict__ Fx) {
  int t = blockIdx.x * 64 + threadIdx.x;
  if (t < 128) {
    float s = 0.f;
    for (int a = 0; a < 512; ++a) s = fmaf(H[(512 + t) * 1152 + a], x0[a], s);
    xc[t] = -s;
  } else if (t < 640) {
    int r = t - 128;
    float s = 0.f;
    for (int b = 0; b < 512; ++b) s = fmaf(H[(640 + r) * 1152 + b], x0[b], s);
    Fx[r] = s;
  }
}

// ---------------- LU (no pivoting), blocked 64, of A (512x512, row-major) ----------------
// diag block factor: single wave, column-per-lane in registers, shuffle broadcasts
__global__ __launch_bounds__(64) void k_lu_diag(float* __restrict__ A, int kb) {
  const int lane = threadIdx.x;
  float* blk = A + kb * 64 * 512 + kb * 64;
  float col[64];
  #pragma unroll
  for (int r = 0; r < 64; ++r) col[r] = blk[r * 512 + lane];
  float invp = 1.0f;
  #pragma unroll
  for (int k = 0; k < 64; ++k) {
    float piv = __shfl(col[k], k);
    float inv = 1.0f / piv;
    if (lane == k) invp = inv;
    float m = col[k] * inv;          // valid for lane > k
    bool act = lane > k;
    #pragma unroll
    for (int r = k + 1; r < 64; ++r) {
      float ckr = __shfl(col[r], k); // pivot column (lane k), unscaled
      if (act) col[r] -= ckr * m;
    }
  }
  #pragma unroll
  for (int r = 0; r < 64; ++r) {
    if (r > lane) col[r] *= invp;    // scale L part of own column
    blk[r * 512 + lane] = col[r];
  }
}

// panels: U-panel (unit-L forward solve per column), L-panel (row / U solve)
__global__ __launch_bounds__(256) void k_lu_panels(float* __restrict__ A, int kb) {
  __shared__ float sD[64 * 65];
  const int t = threadIdx.x;
  #pragma unroll
  for (int l = 0; l < 16; ++l) {
    int idx = t + l * 256;
    int r = idx >> 6, c = idx & 63;
    sD[r * 65 + c] = A[(kb * 64 + r) * 512 + kb * 64 + c];
  }
  __syncthreads();
  const int rem = 512 - 64 * (kb + 1);
  const int nvec = 2 * rem;
  const int lane = t & 63;
  int gwave = blockIdx.x * 4 + (t >> 6);
  const int totalWaves = gridDim.x * 4;
  for (int vec = gwave; vec < nvec; vec += totalWaves) {
    if (vec < rem) {
      // U-panel column c: solve unit-L * u = a
      int c = 64 * (kb + 1) + vec;
      float v0 = A[(kb * 64 + lane) * 512 + c];
      for (int ii = 1; ii < 64; ++ii) {
        float s = (lane < ii) ? sD[ii * 65 + lane] * v0 : 0.f;
        s = wave_sum(s);
        if (lane == ii) v0 -= s;
      }
      A[(kb * 64 + lane) * 512 + c] = v0;
    } else {
      // L-panel row r: solve x * U = a
      int r = 64 * (kb + 1) + (vec - rem);
      float v0 = A[r * 512 + kb * 64 + lane];
      for (int ii = 0; ii < 64; ++ii) {
        float s = (lane < ii) ? v0 * sD[lane * 65 + ii] : 0.f;
        s = wave_sum(s);
        if (lane == ii) v0 = (v0 - s) / sD[ii * 65 + ii];
      }
      A[r * 512 + kb * 64 + lane] = v0;
    }
  }
}

// trailing update: A22 -= L21 * U12, 64x64 tiles, K=64
__global__ __launch_bounds__(256) void k_lu_trailing(float* __restrict__ A, int kb) {
  __shared__ float sL[32][65]; // [k][m]
  __shared__ float sU[32][65]; // [k][n]
  const int t = threadIdx.x;
  const int base = 64 * (kb + 1);
  const int r0 = base + blockIdx.y * 64, c0 = base + blockIdx.x * 64;
  const int tj = t & 15, ti = t >> 4;
  float acc[4][4] = {};
  for (int k0 = 0; k0 < 64; k0 += 32) {
    #pragma unroll
    for (int l = 0; l < 2; ++l) {
      int idx = t + l * 256;
      int row = idx >> 3, k4 = (idx & 7) << 2;
      float4 v = *(const float4*)&A[(r0 + row) * 512 + kb * 64 + k0 + k4];
      sL[k4 + 0][row] = v.x; sL[k4 + 1][row] = v.y; sL[k4 + 2][row] = v.z; sL[k4 + 3][row] = v.w;
      int kk = idx >> 4, c4 = (idx & 15) << 2;
      float4 u4 = *(const float4*)&A[(kb * 64 + k0 + kk) * 512 + c0 + c4];
      sU[kk][c4 + 0] = u4.x; sU[kk][c4 + 1] = u4.y; sU[kk][c4 + 2] = u4.z; sU[kk][c4 + 3] = u4.w;
    }
    __syncthreads();
    #pragma unroll
    for (int kk = 0; kk < 32; ++kk) {
      float am[4], bn[4];
      #pragma unroll
      for (int q = 0; q < 4; ++q) am[q] = sL[kk][ti * 4 + q];
      #pragma unroll
      for (int q = 0; q < 4; ++q) bn[q] = sU[kk][tj * 4 + q];
      #pragma unroll
      for (int r = 0; r < 4; ++r)
        #pragma unroll
        for (int c = 0; c < 4; ++c)
          acc[r][c] = fmaf(am[r], bn[c], acc[r][c]);
    }
    __syncthreads();
  }
  #pragma unroll
  for (int r = 0; r < 4; ++r) {
    float4 old = *(float4*)&A[(r0 + ti * 4 + r) * 512 + c0 + tj * 4];
    old.x -= acc[r][0]; old.y -= acc[r][1]; old.z -= acc[r][2]; old.w -= acc[r][3];
    *(float4*)&A[(r0 + ti * 4 + r) * 512 + c0 + tj * 4] = old;
  }
}

// ---------------- triangular solves: A (=LU) * Gt = C2^T ----------------
__global__ __launch_bounds__(256) void k_trsm_fwd(const float* __restrict__ A, const float* __restrict__ C2,
                                                  float* __restrict__ Gt) {
  const int lane = threadIdx.x & 63;
  const int o = (blockIdx.x * 256 + threadIdx.x) >> 6;
  if (o >= 128) return;
  float v[8];
  #pragma unroll
  for (int m = 0; m < 8; ++m) v[m] = C2[o * 512 + m * 64 + lane];
  #pragma unroll
  for (int om = 0; om < 8; ++om) {
    for (int ii = 0; ii < 64; ++ii) {
      int i = om * 64 + ii;
      const float* Arow = A + i * 512;
      float s = 0.f;
      #pragma unroll
      for (int m = 0; m < om; ++m) s = fmaf(Arow[m * 64 + lane], v[m], s);
      {
        float l = Arow[om * 64 + lane];
        s += (lane < ii) ? l * v[om] : 0.f;
      }
      s = wave_sum(s);
      if (lane == ii) v[om] -= s;
    }
  }
  #pragma unroll
  for (int m = 0; m < 8; ++m) Gt[(m * 64 + lane) * 128 + o] = v[m];
}

__global__ __launch_bounds__(256) void k_trsm_bwd(const float* __restrict__ A, float* __restrict__ Gt) {
  const int lane = threadIdx.x & 63;
  const int o = (blockIdx.x * 256 + threadIdx.x) >> 6;
  if (o >= 128) return;
  float v[8];
  #pragma unroll
  for (int m = 0; m < 8; ++m) v[m] = Gt[(m * 64 + lane) * 128 + o];
  #pragma unroll
  for (int om = 7; om >= 0; --om) {
    for (int ii = 63; ii >= 0; --ii) {
      int i = om * 64 + ii;
      const float* Arow = A + i * 512;
      float s = 0.f;
      #pragma unroll
      for (int m = om + 1; m < 8; ++m) s = fmaf(Arow[m * 64 + lane], v[m], s);
      {
        float uu = Arow[om * 64 + lane];
        s += (lane > ii) ? uu * v[om] : 0.f;
      }
      s = wave_sum(s);
      if (lane == ii) v[om] = (v[om] - s) / Arow[i];
    }
  }
  #pragma unroll
  for (int m = 0; m < 8; ++m) Gt[(m * 64 + lane) * 128 + o] = v[m];
}

// ---------------- W1 = G@B1 + D21, W2 = G@B2 + D22, bias = G@Fx ----------------
__global__ void k_wass(const float* __restrict__ Gt, const float* __restrict__ H,
                       const float* __restrict__ B2, const float* __restrict__ D21,
                       const float* __restrict__ D22, const float* __restrict__ Fx,
                       float* __restrict__ W1, float* __restrict__ W2, float* __restrict__ bias) {
  int idx = blockIdx.x * 256 + threadIdx.x;
  if (idx < 16384) {
    int o = idx >> 7, j = idx & 127;
    float s = 0.f;
    for (int a = 0; a < 512; ++a) s = fmaf(Gt[a * 128 + o], H[(640 + a) * 1152 + 512 + j], s);
    W1[idx] = s + D21[idx];
  } else if (idx < 32768) {
    int q = idx - 16384;
    int o = q >> 7, j = q & 127;
    float s = 0.f;
    for (int a = 0; a < 512; ++a) s = fmaf(Gt[a * 128 + o], B2[a * 128 + j], s);
    W2[q] = s + D22[q];
  } else if (idx < 32768 + 128) {
    int o = idx - 32768;
    float s = 0.f;
    for (int a = 0; a < 512; ++a) s = fmaf(Gt[a * 128 + o], Fx[a], s);
    bias[o] = s;
  }
}

// ---------------- baseT[i][b] = xc[i] + (u @ D12^T)[b][i] ----------------
__global__ __launch_bounds__(256) void k_ud(const float* __restrict__ u, const float* __restrict__ D12,
                                            const float* __restrict__ xc, float* __restrict__ baseT) {
  __shared__ float sU[32][65]; // [k][m=b]
  __shared__ float sD[32][65]; // [k][n=i]
  const int t = threadIdx.x;
  const int b0 = blockIdx.x * 64, i0 = blockIdx.y * 64;
  const int tm = t & 15, tn = t >> 4;
  float acc[4][4] = {}; // [n][m]
  for (int k0 = 0; k0 < 128; k0 += 32) {
    #pragma unroll
    for (int l = 0; l < 2; ++l) {
      int idx = t + l * 256;
      int row = idx >> 3, k4 = (idx & 7) << 2;
      float4 v = *(const float4*)&u[(b0 + row) * 128 + k0 + k4];
      sU[k4 + 0][row] = v.x; sU[k4 + 1][row] = v.y; sU[k4 + 2][row] = v.z; sU[k4 + 3][row] = v.w;
      float4 d = *(const float4*)&D12[(i0 + row) * 128 + k0 + k4];
      sD[k4 + 0][row] = d.x; sD[k4 + 1][row] = d.y; sD[k4 + 2][row] = d.z; sD[k4 + 3][row] = d.w;
    }
    __syncthreads();
    #pragma unroll
    for (int kk = 0; kk < 32; ++kk) {
      float mm[4], nn[4];
      #pragma unroll
      for (int q = 0; q < 4; ++q) mm[q] = sU[kk][tm * 4 + q];
      #pragma unroll
      for (int q = 0; q < 4; ++q) nn[q] = sD[kk][tn * 4 + q];
      #pragma unroll
      for (int c = 0; c < 4; ++c)
        #pragma unroll
        for (int r = 0; r < 4; ++r)
          acc[c][r] = fmaf(nn[c], mm[r], acc[c][r]);
    }
    __syncthreads();
  }
  #pragma unroll
  for (int c = 0; c < 4; ++c) {
    int i = i0 + tn * 4 + c;
    float xcv = xc[i];
    float4 v = make_float4(acc[c][0] + xcv, acc[c][1] + xcv, acc[c][2] + xcv, acc[c][3] + xcv);
    *(float4*)&baseT[i * BATCH + b0 + tm * 4] = v;
  }
}

// ---------------- scan: w[i] = tanh((base_i + sum_{j<i} D11[i][j] w[j]) / Lam[i]) ----------------
__global__ __launch_bounds__(64) void k_scan(const float* __restrict__ baseT, const float* __restrict__ D11g,
                                             const float* __restrict__ Lam, float* __restrict__ wT) {
  __shared__ float sD[128 * 128];
  __shared__ float srl[128];
  const int tid = threadIdx.x;
  for (int l = 0; l < 64; ++l) {
    int idx = tid + l * 64;
    *(float4*)&sD[idx * 4] = *(const float4*)&D11g[idx * 4];
  }
  #pragma unroll
  for (int l = 0; l < 2; ++l) {
    int i = tid + l * 64;
    srl[i] = 1.0f / Lam[i];
  }
  __syncthreads();
  const int b = blockIdx.x * 64 + tid;
  float w[128];
  #pragma unroll
  for (int i = 0; i < 128; ++i) {
    float acc = baseT[i * BATCH + b];
    #pragma unroll
    for (int j = 0; j < i; ++j) acc = fmaf(w[j], sD[i * 128 + j], acc);
    w[i] = tanhf(acc * srl[i]);
    wT[i * BATCH + b] = w[i];
  }
}

// ---------------- y = w@W1^T + u@W2^T + bias ----------------
__global__ __launch_bounds__(256) void k_y(const float* __restrict__ wT, const float* __restrict__ u,
                                           const float* __restrict__ W1, const float* __restrict__ W2,
                                           const float* __restrict__ bias, float* __restrict__ y) {
  __shared__ float sA[32][65]; // [k][m=b]
  __shared__ float sW[32][65]; // [k][n=o]
  const int t = threadIdx.x;
  const int b0 = blockIdx.x * 64, o0 = blockIdx.y * 64;
  const int tn = t & 15, tm = t >> 4;
  float acc[4][4] = {}; // [m][n]
  // pass 1: wT (k-major) x W1
  for (int k0 = 0; k0 < 128; k0 += 32) {
    #pragma unroll
    for (int l = 0; l < 2; ++l) {
      int idx = t + l * 256;
      int kk = idx >> 4, c4 = (idx & 15) << 2;
      float4 v = *(const float4*)&wT[(k0 + kk) * BATCH + b0 + c4];
      sA[kk][c4 + 0] = v.x; sA[kk][c4 + 1] = v.y; sA[kk][c4 + 2] = v.z; sA[kk][c4 + 3] = v.w;
      int row = idx >> 3, k4 = (idx & 7) << 2;
      float4 d = *(const float4*)&W1[(o0 + row) * 128 + k0 + k4];
      sW[k4 + 0][row] = d.x; sW[k4 + 1][row] = d.y; sW[k4 + 2][row] = d.z; sW[k4 + 3][row] = d.w;
    }
    __syncthreads();
    #pragma unroll
    for (int kk = 0; kk < 32; ++kk) {
      float mm[4], nn[4];
      #pragma unroll
      for (int q = 0; q < 4; ++q) mm[q] = sA[kk][tm * 4 + q];
      #pragma unroll
      for (int q = 0; q < 4; ++q) nn[q] = sW[kk][tn * 4 + q];
      #pragma unroll
      for (int r = 0; r < 4; ++r)
        #pragma unroll
        for (int c = 0; c < 4; ++c)
          acc[r][c] = fmaf(mm[r], nn[c], acc[r][c]);
    }
    __syncthreads();
  }
  // pass 2: u (m-major, transpose in LDS) x W2
  for (int k0 = 0; k0 < 128; k0 += 32) {
    #pragma unroll
    for (int l = 0; l < 2; ++l) {
      int idx = t + l * 256;
      int row = idx >> 3, k4 = (idx & 7) << 2;
      float4 v = *(const float4*)&u[(b0 + row) * 128 + k0 + k4];
      sA[k4 + 0][row] = v.x; sA[k4 + 1][row] = v.y; sA[k4 + 2][row] = v.z; sA[k4 + 3][row] = v.w;
      float4 d = *(const float4*)&W2[(o0 + row) * 128 + k0 + k4];
      sW[k4 + 0][row] = d.x; sW[k4 + 1][row] = d.y; sW[k4 + 2][row] = d.z; sW[k4 + 3][row] = d.w;
    }
    __syncthreads();
    #pragma unroll
    for (int kk = 0; kk < 32; ++kk) {
      float mm[4], nn[4];
      #pragma unroll
      for (int q = 0; q < 4; ++q) mm[q] = sA[kk][tm * 4 + q];
      #pragma unroll
      for (int q = 0; q < 4; ++q) nn[q] = sW[kk][tn * 4 + q];
      #pragma unroll
      for (int r = 0; r < 4; ++r)
        #pragma unroll
        for (int c = 0; c < 4; ++c)
          acc[r][c] = fmaf(mm[r], nn[c], acc[r][c]);
    }
    __syncthreads();
  }
  #pragma unroll
  for (int r = 0; r < 4; ++r) {
    int bb = b0 + tm * 4 + r;
    float4 v = make_float4(acc[r][0] + bias[o0 + tn * 4 + 0],
                           acc[r][1] + bias[o0 + tn * 4 + 1],
                           acc[r][2] + bias[o0 + tn * 4 + 2],
                           acc[r][3] + bias[o0 + tn * 4 + 3]);
    *(float4*)&y[bb * 128 + o0 + tn * 4] = v;
  }
}

extern "C" void kernel_launch(void* const* d_in, const int* in_sizes, int n_in,
                              void* d_out, int out_size, void* d_ws, size_t ws_size,
                              hipStream_t stream) {
  const float* u   = (const float*)d_in[0];
  const float* X   = (const float*)d_in[1];
  const float* Y   = (const float*)d_in[2];
  const float* B2  = (const float*)d_in[3];
  const float* C2  = (const float*)d_in[4];
  const float* D21 = (const float*)d_in[5];
  const float* D22 = (const float*)d_in[6];
  const float* D12 = (const float*)d_in[7];
  const float* x0  = (const float*)d_in[8];

  float* ws = (float*)d_ws;
  float* H     = ws;                    // 1152*1152 = 1327104
  float* A     = H + 1327104;           // 512*512   = 262144
  float* Gt    = A + 262144;            // 512*128   = 65536
  float* W1    = Gt + 65536;            // 16384
  float* W2    = W1 + 16384;            // 16384
  float* D11   = W2 + 16384;            // 16384
  float* Lam   = D11 + 16384;           // 128
  float* xc    = Lam + 128;             // 128
  float* Fx    = xc + 128;              // 512
  float* bias  = Fx + 512;              // 128
  float* baseT = bias + 128;            // 128*16384 = 2097152
  float* wT    = baseT + 2097152;       // 2097152
  float* y     = (float*)d_out;

  k_xtx<<<dim3(18, 18), 256, 0, stream>>>(X, H);
  k_assemble<<<(512 * 512 + 128 * 128 + 128 + 255) / 256, 256, 0, stream>>>(H, Y, A, D11, Lam);
  k_xcfx<<<10, 64, 0, stream>>>(H, x0, xc, Fx);

  for (int kb = 0; kb < 8; ++kb) {
    k_lu_diag<<<1, 64, 0, stream>>>(A, kb);
    if (kb < 7) {
      k_lu_panels<<<64, 256, 0, stream>>>(A, kb);
      int nb = 7 - kb;
      k_lu_trailing<<<dim3(nb, nb), 256, 0, stream>>>(A, kb);
    }
  }

  k_trsm_fwd<<<32, 256, 0, stream>>>(A, C2, Gt);
  k_trsm_bwd<<<32, 256, 0, stream>>>(A, Gt);
  k_wass<<<(32768 + 128 + 255) / 256, 256, 0, stream>>>(Gt, H, B2, D21, D22, Fx, W1, W2, bias);

  k_ud<<<dim3(256, 2), 256, 0, stream>>>(u, D12, xc, baseT);
  k_scan<<<256, 64, 0, stream>>>(baseT, D11, Lam, wT);
  k_y<<<dim3(256, 2), 256, 0, stream>>>(wT, u, W1, W2, bias, y);
}